// Round 6
// baseline (244.035 us; speedup 1.0000x reference)
//
#include <hip/hip_runtime.h>

#define MTOT 16384        // 8*2048 tokens
#define NFEAT 512         // out features
#define KTOT 4608         // 512 inputs * 9 segments

typedef float f32x16 __attribute__((ext_vector_type(16)));
typedef short s16x8 __attribute__((ext_vector_type(8)));

__device__ __forceinline__ int div9(int c) { return (c * 7282) >> 16; }  // exact for 0 <= c < 32768

// decode 8-bit one-hot mask -> 8 bf16 one-hot fragment (~14 VALU)
__device__ __forceinline__ s16x8 decode_mask(unsigned msk) {
  unsigned e0 = (msk & 15u) * 0x00204081u & 0x01010101u;   // bytes = bits 0..3
  unsigned e1 = (msk >> 4)  * 0x00204081u & 0x01010101u;   // bytes = bits 4..7
  unsigned d0 = __builtin_amdgcn_perm(e0, e0, 0x0C010C00u) * 0x3F80u;  // shorts {bit0,bit1}
  unsigned d1 = __builtin_amdgcn_perm(e0, e0, 0x0C030C02u) * 0x3F80u;  // shorts {bit2,bit3}
  unsigned d2 = __builtin_amdgcn_perm(e1, e1, 0x0C010C00u) * 0x3F80u;  // shorts {bit4,bit5}
  unsigned d3 = __builtin_amdgcn_perm(e1, e1, 0x0C030C02u) * 0x3F80u;  // shorts {bit6,bit7}
  union { unsigned d[4]; s16x8 v; } u;
  u.d[0] = d0; u.d[1] = d1; u.d[2] = d2; u.d[3] = d3;
  return u.v;
}

// ---------------- fused prep: bx<2048 -> build_b, else build_codes (mask bytes) ----------------
__global__ __launch_bounds__(256) void prep(const float* __restrict__ x,
                                            const float* __restrict__ coeffs,
                                            unsigned char* __restrict__ codeT,
                                            unsigned short* __restrict__ Bmat) {
  __shared__ unsigned char segt[64][68];
  const int bx = blockIdx.x;
  const int tid = threadIdx.x;
  if (bx < 2048) {
    const int i = bx >> 2, q = bx & 3;
    const float* cb = coeffs + (size_t)i * 6144;
#pragma unroll
    for (int p = 0; p < 5; ++p) {
      int kl = p * 256 + tid;
      if (kl < 1152) {
        int k = q * 1152 + kl;
        int j = div9(k), s = k - j * 9;
        float v = cb[j * 12 + s] + cb[j * 12 + s + 1] + cb[j * 12 + s + 2];
        unsigned u = __float_as_uint(v);
        unsigned rn = (u + 0x7FFFu + ((u >> 16) & 1u)) >> 16;  // RNE f32->bf16
        Bmat[(size_t)i * KTOT + k] = (unsigned short)rn;
      }
    }
  } else {
    const int bb = bx - 2048;
    const int mt = bb >> 3;   // 0..255
    const int jt = bb & 7;    // 0..7
    const int m0 = mt * 64;
    const float4* x4 = (const float4*)x;
    const float T1 = (float)(1.0/9.0), T2 = (float)(2.0/9.0), T3 = (float)(3.0/9.0),
                T4 = (float)(4.0/9.0), T5 = (float)(5.0/9.0), T6 = (float)(6.0/9.0),
                T7 = (float)(7.0/9.0), T8 = (float)(8.0/9.0);
#pragma unroll
    for (int it = 0; it < 4; ++it) {
      int f = it * 256 + tid;
      int m = f >> 4, jq = f & 15;
      float4 v = x4[(size_t)(m0 + m) * 128 + jt * 16 + jq];
      uchar4 sv;
      { float xv = v.x; sv.x = (unsigned char)((xv>=T1)+(xv>=T2)+(xv>=T3)+(xv>=T4)+(xv>=T5)+(xv>=T6)+(xv>=T7)+(xv>=T8)); }
      { float xv = v.y; sv.y = (unsigned char)((xv>=T1)+(xv>=T2)+(xv>=T3)+(xv>=T4)+(xv>=T5)+(xv>=T6)+(xv>=T7)+(xv>=T8)); }
      { float xv = v.z; sv.z = (unsigned char)((xv>=T1)+(xv>=T2)+(xv>=T3)+(xv>=T4)+(xv>=T5)+(xv>=T6)+(xv>=T7)+(xv>=T8)); }
      { float xv = v.w; sv.w = (unsigned char)((xv>=T1)+(xv>=T2)+(xv>=T3)+(xv>=T4)+(xv>=T5)+(xv>=T6)+(xv>=T7)+(xv>=T8)); }
      *(uchar4*)&segt[m][jq * 4] = sv;
    }
    __syncthreads();
#pragma unroll
    for (int p = 0; p < 5; ++p) {
      int u = p * 256 + tid;
      if (u < 1152) {
        int gl = u >> 4, mq = u & 15;
        int c0 = jt * 576 + gl * 8;
        int j0 = div9(c0), j1 = div9(c0 + 7);
        int j0l = j0 - jt * 64, j1l = j1 - jt * 64;
        uchar4 ob;
        unsigned char* pb = (unsigned char*)&ob;
#pragma unroll
        for (int c = 0; c < 4; ++c) {
          int m = mq * 4 + c;
          int s0 = segt[m][j0l];
          int pos0 = j0 * 9 + s0 - c0;
          unsigned code = (pos0 >= 0 && pos0 < 8) ? (1u << pos0) : 0u;
          if (j1 != j0) {
            int s1 = segt[m][j1l];
            int pos1 = j1 * 9 + s1 - c0;
            if (pos1 < 8) code |= (1u << pos1);
          }
          pb[c] = (unsigned char)code;
        }
        *(uchar4*)(codeT + (size_t)(jt * 72 + gl) * MTOT + m0 + mq * 4) = ob;
      }
    }
  }
}

// ---------------- main: 32x32x16 MFMA, NO LDS / NO BARRIERS ----------------
// Block = 64m x 256n, 4 waves split n (wave = 64m x 64n). B frags global->VGPR,
// register double-buffered; waves free-run with compiler-scheduled vmcnt(N).
__global__ __launch_bounds__(256, 2) void kan_gemm(const unsigned char* __restrict__ codeT,
                                                   const unsigned short* __restrict__ Bmat,
                                                   float* __restrict__ out) {
  const int tid = threadIdx.x;
  const int lane = tid & 63;
  const int wid = tid >> 6;   // 4 waves, split n
  const int l5 = lane & 31;
  const int lh = lane >> 5;   // k-half within fragment
  const int bx = blockIdx.x;
  const int ntb = bx & 1;     // n half: XCD i holds only half of Bmat (2.36 MB) in L2
  const int mt = bx >> 1;     // 0..255
  const int m0 = mt * 64;
  const int n0w = ntb * 256 + wid * 64;  // wave's 64 n-cols

  // B frag (ns,ks): Bmat[(n0w + ns*32 + l5)*KTOT + kt*64 + ks*16 + lh*8], 16B/lane
  const unsigned short* gB0 = Bmat + (size_t)(n0w + l5) * KTOT + lh * 8;       // ns=0
  const unsigned short* gB1 = Bmat + (size_t)(n0w + 32 + l5) * KTOT + lh * 8;  // ns=1
  // code frag (ms,ks): codeT[(kt*8 + ks*2 + lh)*MTOT + m0 + ms*32 + l5]
  const unsigned char* gCk0 = codeT + (size_t)(0 * 2 + lh) * MTOT + m0 + l5;
  const unsigned char* gCk1 = codeT + (size_t)(1 * 2 + lh) * MTOT + m0 + l5;
  const unsigned char* gCk2 = codeT + (size_t)(2 * 2 + lh) * MTOT + m0 + l5;
  const unsigned char* gCk3 = codeT + (size_t)(3 * 2 + lh) * MTOT + m0 + l5;

  f32x16 acc[2][2] = {};          // [ms][ns]
  s16x8 bA[8], bB[8];             // [ns*4+ks], register double-buffer
  unsigned char crA[8], crB[8];   // [ms*4+ks]

#define LOAD_B(BX) do { \
    _Pragma("unroll") \
    for (int ks = 0; ks < 4; ++ks) { \
      BX[ks]     = *(const s16x8*)(gB0 + ks * 16); \
      BX[4 + ks] = *(const s16x8*)(gB1 + ks * 16); \
    } \
    gB0 += 64; gB1 += 64; } while (0)

#define LOAD_CR(CR) do { \
    CR[0] = gCk0[0];  CR[4] = gCk0[32]; \
    CR[1] = gCk1[0];  CR[5] = gCk1[32]; \
    CR[2] = gCk2[0];  CR[6] = gCk2[32]; \
    CR[3] = gCk3[0];  CR[7] = gCk3[32]; \
    gCk0 += (size_t)8 * MTOT; gCk1 += (size_t)8 * MTOT; \
    gCk2 += (size_t)8 * MTOT; gCk3 += (size_t)8 * MTOT; } while (0)

#define COMPUTE(BX, CR) do { \
    _Pragma("unroll") \
    for (int ks = 0; ks < 4; ++ks) { \
      _Pragma("unroll") \
      for (int ms = 0; ms < 2; ++ms) { \
        s16x8 a = decode_mask(CR[ms * 4 + ks]); \
        acc[ms][0] = __builtin_amdgcn_mfma_f32_32x32x16_bf16(a, BX[ks],     acc[ms][0], 0, 0, 0); \
        acc[ms][1] = __builtin_amdgcn_mfma_f32_32x32x16_bf16(a, BX[4 + ks], acc[ms][1], 0, 0, 0); \
      } \
    } } while (0)

  // prologue: load kt=0 -> (bA,crA), kt=1 -> (bB,crB)
  LOAD_B(bA); LOAD_CR(crA);
  LOAD_B(bB); LOAD_CR(crB);

#pragma unroll 1
  for (int kt = 0; kt < 72; kt += 2) {
    COMPUTE(bA, crA);               // 16 MFMA, covers bB/crB in-flight latency
    if (kt < 70) { LOAD_B(bA); LOAD_CR(crA); }   // kt+2
    COMPUTE(bB, crB);
    if (kt < 70) { LOAD_B(bB); LOAD_CR(crB); }   // kt+3
  }

  // epilogue: 32x32 C/D layout col=lane&31, row=(reg&3)+8*(reg>>2)+4*(lane>>5)
#pragma unroll
  for (int ms = 0; ms < 2; ++ms) {
#pragma unroll
    for (int ns = 0; ns < 2; ++ns) {
      int rowbase = m0 + ms * 32 + 4 * lh;
      int col = n0w + ns * 32 + l5;
      float* op = out + (size_t)rowbase * NFEAT + col;
#pragma unroll
      for (int rg = 0; rg < 16; ++rg) {
        int row_off = (rg & 3) + 8 * (rg >> 2);
        op[(size_t)row_off * NFEAT] = acc[ms][ns][rg];
      }
    }
  }
}

extern "C" void kernel_launch(void* const* d_in, const int* in_sizes, int n_in,
                              void* d_out, int out_size, void* d_ws, size_t ws_size,
                              hipStream_t stream) {
  const float* x = (const float*)d_in[0];        // [16384, 512] f32
  const float* coeffs = (const float*)d_in[1];   // [512, 512, 12] f32
  float* out = (float*)d_out;                    // [16384, 512] f32
  unsigned char* codeT = (unsigned char*)d_ws;                                  // 576*16384 = 9.44 MB
  unsigned short* Bmat = (unsigned short*)((char*)d_ws + (size_t)576 * MTOT);   // 512*4608*2 = 4.72 MB

  prep<<<dim3(4096), dim3(256), 0, stream>>>(x, coeffs, codeT, Bmat);
  kan_gemm<<<dim3(512), dim3(256), 0, stream>>>(codeT, Bmat, out);
}

// Round 7
// 178.756 us; speedup vs baseline: 1.3652x; 1.3652x over previous
//
#include <hip/hip_runtime.h>

#define MTOT 16384        // 8*2048 tokens
#define NFEAT 512         // out features
#define KTOT 4608         // 512 inputs * 9 segments

typedef float f32x16 __attribute__((ext_vector_type(16)));
typedef short s16x8 __attribute__((ext_vector_type(8)));

__device__ __forceinline__ int div9(int c) { return (c * 7282) >> 16; }  // exact for 0 <= c < 32768

#define GLDS(GP, LP) __builtin_amdgcn_global_load_lds( \
    (const __attribute__((address_space(1))) void*)(GP), \
    (__attribute__((address_space(3))) void*)(LP), 16, 0, 0)

// decode 8-bit one-hot mask -> 8 bf16 one-hot fragment (~10 VALU)
__device__ __forceinline__ s16x8 decode_mask(unsigned msk) {
  unsigned e0 = (msk & 15u) * 0x00204081u & 0x01010101u;   // bytes = bits 0..3
  unsigned e1 = (msk >> 4)  * 0x00204081u & 0x01010101u;   // bytes = bits 4..7
  unsigned d0 = __builtin_amdgcn_perm(e0, e0, 0x0C010C00u) * 0x3F80u;  // shorts {bit0,bit1}
  unsigned d1 = __builtin_amdgcn_perm(e0, e0, 0x0C030C02u) * 0x3F80u;  // shorts {bit2,bit3}
  unsigned d2 = __builtin_amdgcn_perm(e1, e1, 0x0C010C00u) * 0x3F80u;  // shorts {bit4,bit5}
  unsigned d3 = __builtin_amdgcn_perm(e1, e1, 0x0C030C02u) * 0x3F80u;  // shorts {bit6,bit7}
  union { unsigned d[4]; s16x8 v; } u;
  u.d[0] = d0; u.d[1] = d1; u.d[2] = d2; u.d[3] = d3;
  return u.v;
}

// ---------------- fused prep: bx<2048 -> build_b, else build_codes (u64/row/kt) ----------------
__global__ __launch_bounds__(256) void prep(const float* __restrict__ x,
                                            const float* __restrict__ coeffs,
                                            unsigned long long* __restrict__ codeP,
                                            unsigned short* __restrict__ Bmat) {
  __shared__ unsigned char segt[64][68];
  const int bx = blockIdx.x;
  const int tid = threadIdx.x;
  if (bx < 2048) {
    const int i = bx >> 2, q = bx & 3;
    const float* cb = coeffs + (size_t)i * 6144;
#pragma unroll
    for (int p = 0; p < 5; ++p) {
      int kl = p * 256 + tid;
      if (kl < 1152) {
        int k = q * 1152 + kl;
        int j = div9(k), s = k - j * 9;
        float v = cb[j * 12 + s] + cb[j * 12 + s + 1] + cb[j * 12 + s + 2];
        unsigned u = __float_as_uint(v);
        unsigned rn = (u + 0x7FFFu + ((u >> 16) & 1u)) >> 16;  // RNE f32->bf16
        Bmat[(size_t)i * KTOT + k] = (unsigned short)rn;
      }
    }
  } else {
    const int bb = bx - 2048;
    const int mt = bb >> 3;   // 0..255 (64 tokens)
    const int jt = bb & 7;    // 0..7   (64 inputs -> 72 groups -> 9 kt)
    const int m0 = mt * 64;
    const float4* x4 = (const float4*)x;
    const float T1 = (float)(1.0/9.0), T2 = (float)(2.0/9.0), T3 = (float)(3.0/9.0),
                T4 = (float)(4.0/9.0), T5 = (float)(5.0/9.0), T6 = (float)(6.0/9.0),
                T7 = (float)(7.0/9.0), T8 = (float)(8.0/9.0);
#pragma unroll
    for (int it = 0; it < 4; ++it) {
      int f = it * 256 + tid;
      int m = f >> 4, jq = f & 15;
      float4 v = x4[(size_t)(m0 + m) * 128 + jt * 16 + jq];
      uchar4 sv;
      { float xv = v.x; sv.x = (unsigned char)((xv>=T1)+(xv>=T2)+(xv>=T3)+(xv>=T4)+(xv>=T5)+(xv>=T6)+(xv>=T7)+(xv>=T8)); }
      { float xv = v.y; sv.y = (unsigned char)((xv>=T1)+(xv>=T2)+(xv>=T3)+(xv>=T4)+(xv>=T5)+(xv>=T6)+(xv>=T7)+(xv>=T8)); }
      { float xv = v.z; sv.z = (unsigned char)((xv>=T1)+(xv>=T2)+(xv>=T3)+(xv>=T4)+(xv>=T5)+(xv>=T6)+(xv>=T7)+(xv>=T8)); }
      { float xv = v.w; sv.w = (unsigned char)((xv>=T1)+(xv>=T2)+(xv>=T3)+(xv>=T4)+(xv>=T5)+(xv>=T6)+(xv>=T7)+(xv>=T8)); }
      *(uchar4*)&segt[m][jq * 4] = sv;
    }
    __syncthreads();
    // 576 items: (t 0..8) x (m 0..63); one u64 (8 group bytes) each
#pragma unroll
    for (int p = 0; p < 3; ++p) {
      int u = p * 256 + tid;
      if (u < 576) {
        int t = u >> 6, m = u & 63;
        unsigned long long w = 0ull;
#pragma unroll
        for (int b = 0; b < 8; ++b) {
          int gl = t * 8 + b;
          int c0 = jt * 576 + gl * 8;
          int j0 = div9(c0), j1 = div9(c0 + 7);
          int s0 = segt[m][j0 - jt * 64];
          int pos0 = j0 * 9 + s0 - c0;
          unsigned code = (pos0 >= 0 && pos0 < 8) ? (1u << pos0) : 0u;
          if (j1 != j0) {
            int s1 = segt[m][j1 - jt * 64];
            int pos1 = j1 * 9 + s1 - c0;
            if (pos1 < 8) code |= (1u << pos1);
          }
          w |= (unsigned long long)code << (8 * b);
        }
        codeP[(size_t)(jt * 9 + t) * MTOT + m0 + m] = w;
      }
    }
  }
}

// ---------------- main: 32x32x16 MFMA, BK=128 phases, packed-u64 codes ----------------
// Block 128m x 64n, 4 waves m-split (wave 32m x 64n). B via glds double-buffer,
// 16 MFMA per wave per barrier; codes one dwordx2 per wave per kt.
__global__ __launch_bounds__(256, 4) void kan_gemm(const unsigned long long* __restrict__ codeP,
                                                   const unsigned short* __restrict__ Bmat,
                                                   float* __restrict__ out) {
  __shared__ __align__(16) short Blds[2][8192];  // 2 x 16KB: 16 slots x 1KB, fragment-major
  const int tid = threadIdx.x;
  const int lane = tid & 63;
  const int wid = tid >> 6;
  const int l5 = lane & 31;
  const int lh = lane >> 5;
  const int lh8 = lh * 8;
  const int bx = blockIdx.x;
  const int nt = bx & 7;      // == XCD id under round-robin: B slice (590 KB) L2-resident
  const int mt = bx >> 3;     // 0..127
  const int m0 = mt * 128, n0 = nt * 64;

  // B staging: wave owns slots s = wid*4+q; ns = s>>3, ksl = s&7
  // src: Bmat[(n0+ns*32+l5)*KTOT + phase*128 + ksl*16 + lh*8]
  const unsigned short* gB[4];
#pragma unroll
  for (int q = 0; q < 4; ++q) {
    int s = wid * 4 + q, ns = s >> 3, ksl = s & 7;
    gB[q] = Bmat + (size_t)(n0 + ns * 32 + l5) * KTOT + ksl * 16 + lh * 8;
  }
  // codes: one u64 per (row, kt); both lh halves read same address (HW broadcast)
  const unsigned long long* gC = codeP + m0 + wid * 32 + l5;

  f32x16 acc[2] = {};          // [ns]
  unsigned crA[4], crB[4];     // [ktlocal*2 + word]

#define LOAD_CR(CR) do { \
    unsigned long long a = gC[0], b = gC[MTOT]; \
    CR[0] = (unsigned)a; CR[1] = (unsigned)(a >> 32); \
    CR[2] = (unsigned)b; CR[3] = (unsigned)(b >> 32); \
    gC += (size_t)2 * MTOT; } while (0)

#define ISSUE_B(buf) do { \
    _Pragma("unroll") \
    for (int q = 0; q < 4; ++q) { \
      GLDS(gB[q], &Blds[buf][0] + (wid * 4 + q) * 512 + lane * 8); \
      gB[q] += 128; \
    } } while (0)

#define COMPUTE(buf, CR) do { \
    _Pragma("unroll") \
    for (int ks = 0; ks < 8; ++ks) { \
      unsigned wrd = CR[((ks >> 2) << 1) | ((ks >> 1) & 1)]; \
      unsigned msk = ((wrd >> ((ks & 1) * 16)) >> lh8) & 0xFFu; \
      s16x8 a = decode_mask(msk); \
      s16x8 b0 = *(const s16x8*)&Blds[buf][ks * 512 + lane * 8]; \
      s16x8 b1 = *(const s16x8*)&Blds[buf][(8 + ks) * 512 + lane * 8]; \
      acc[0] = __builtin_amdgcn_mfma_f32_32x32x16_bf16(a, b0, acc[0], 0, 0, 0); \
      acc[1] = __builtin_amdgcn_mfma_f32_32x32x16_bf16(a, b1, acc[1], 0, 0, 0); \
    } } while (0)

  // prologue: phase 0 staged, phase-0/1 codes in regs
  LOAD_CR(crA);
  ISSUE_B(0);
  LOAD_CR(crB);
  __syncthreads();

#pragma unroll 1
  for (int p = 0; p < 36; p += 2) {
    // even phase: compute p; stage p+1; codes p+2
    ISSUE_B(1);
    COMPUTE(0, crA);
    if (p < 34) LOAD_CR(crA);
    __syncthreads();
    // odd phase: compute p+1; stage p+2; codes p+3
    if (p < 34) ISSUE_B(0);
    COMPUTE(1, crB);
    if (p < 34) LOAD_CR(crB);
    __syncthreads();
  }

  // epilogue: 32x32 C/D layout col=lane&31, row=(reg&3)+8*(reg>>2)+4*(lane>>5)
#pragma unroll
  for (int ns = 0; ns < 2; ++ns) {
    int rowbase = m0 + wid * 32 + 4 * lh;
    int col = n0 + ns * 32 + l5;
    float* op = out + (size_t)rowbase * NFEAT + col;
#pragma unroll
    for (int rg = 0; rg < 16; ++rg) {
      int row_off = (rg & 3) + 8 * (rg >> 2);
      op[(size_t)row_off * NFEAT] = acc[ns][rg];
    }
  }
}

extern "C" void kernel_launch(void* const* d_in, const int* in_sizes, int n_in,
                              void* d_out, int out_size, void* d_ws, size_t ws_size,
                              hipStream_t stream) {
  const float* x = (const float*)d_in[0];        // [16384, 512] f32
  const float* coeffs = (const float*)d_in[1];   // [512, 512, 12] f32
  float* out = (float*)d_out;                    // [16384, 512] f32
  unsigned long long* codeP = (unsigned long long*)d_ws;                             // 72*16384*8 = 9.44 MB
  unsigned short* Bmat = (unsigned short*)((char*)d_ws + (size_t)72 * MTOT * 8);     // 512*4608*2 = 4.72 MB

  prep<<<dim3(4096), dim3(256), 0, stream>>>(x, coeffs, codeP, Bmat);
  kan_gemm<<<dim3(1024), dim3(256), 0, stream>>>(codeP, Bmat, out);
}